// Round 15
// baseline (337.051 us; speedup 1.0000x reference)
//
#include <hip/hip_runtime.h>
#include <cstdint>
#include <cstddef>

typedef __attribute__((ext_vector_type(4))) float f32x4;
typedef __attribute__((ext_vector_type(16))) float f32x16;
typedef __attribute__((ext_vector_type(8))) short bf16x8;
typedef __attribute__((ext_vector_type(2))) unsigned int u32x2;

#define S_LEN   2048
#define HID     4096
#define NH      32
#define NKV     8
#define HD      128
#define QKV_N   6144   /* 4096 Q + 1024 K + 1024 V */

typedef const __attribute__((address_space(1))) unsigned int* gptr_t;
typedef __attribute__((address_space(3))) unsigned int* lptr_t;

__device__ __forceinline__ void gload_lds16(const void* g, void* l) {
  __builtin_amdgcn_global_load_lds((gptr_t)g, (lptr_t)l, 16, 0, 0);
}

__device__ __forceinline__ ushort f2bf(float f) {
  union { float f; uint32_t u; } v; v.f = f;
  uint32_t r = v.u + 0x7FFFu + ((v.u >> 16) & 1u);
  return (ushort)(r >> 16);
}
__device__ __forceinline__ float bf2f(ushort u) {
  union { uint32_t u; float f; } v; v.u = ((uint32_t)u) << 16;
  return v.f;
}

// ---------------- fused prep: hs cast + all 4 weight transposes (one launch) ----------------
// Blocks [0,8192): cast hs f32->bf16. Blocks [8192,18432): 64x64 transpose+cast tiles,
// float4 reads + ushort4 writes (G13 — R14's 1-ushort writes were 25% write efficiency).
__global__ void prep_all(const float* __restrict__ hs,
                         const float* __restrict__ Wq, const float* __restrict__ Wk,
                         const float* __restrict__ Wv, const float* __restrict__ Wo,
                         ushort* __restrict__ hsb,
                         ushort* __restrict__ WqkvT, ushort* __restrict__ WoT) {
  int id = blockIdx.x;
  if (id < 8192) {
    int i = (id * 256 + (int)threadIdx.x) * 4;
    float4 v = *reinterpret_cast<const float4*>(hs + i);
    ushort4 o;
    o.x = f2bf(v.x); o.y = f2bf(v.y); o.z = f2bf(v.z); o.w = f2bf(v.w);
    *reinterpret_cast<ushort4*>(hsb + i) = o;
    return;
  }
  __shared__ float t[64][69];   // pad 69: read side (row=4*tx+j, col fixed) is 2-way = free
  id -= 8192;
  const float* src; ushort* dst; int C, local;
  if (id < 4096)        { src = Wq; dst = WqkvT;                      C = 4096; local = id; }
  else if (id < 5120)   { src = Wk; dst = WqkvT + (size_t)4096 * HID; C = 1024; local = id - 4096; }
  else if (id < 6144)   { src = Wv; dst = WqkvT + (size_t)5120 * HID; C = 1024; local = id - 5120; }
  else                  { src = Wo; dst = WoT;                        C = 4096; local = id - 6144; }
  const int cb = C >> 6;
  int bx = local % cb, by = local / cb;
  int tx = threadIdx.x & 15, ty = threadIdx.x >> 4;  // 16 x 16
  int r0 = by * 64, c0 = bx * 64;
#pragma unroll
  for (int i = 0; i < 4; ++i) {
    float4 v = *reinterpret_cast<const float4*>(&src[(size_t)(r0 + ty + i * 16) * C + c0 + tx * 4]);
    t[ty + i * 16][tx * 4 + 0] = v.x;
    t[ty + i * 16][tx * 4 + 1] = v.y;
    t[ty + i * 16][tx * 4 + 2] = v.z;
    t[ty + i * 16][tx * 4 + 3] = v.w;
  }
  __syncthreads();
#pragma unroll
  for (int i = 0; i < 4; ++i) {
    int cc = ty + i * 16;
    ushort4 o;
    o.x = f2bf(t[tx * 4 + 0][cc]);
    o.y = f2bf(t[tx * 4 + 1][cc]);
    o.z = f2bf(t[tx * 4 + 2][cc]);
    o.w = f2bf(t[tx * 4 + 3][cc]);
    *reinterpret_cast<ushort4*>(&dst[(size_t)(c0 + cc) * 4096 + r0 + tx * 4]) = o;
  }
}

// ---------------- GEMM: C[M][N] = A[M][K] * B^T  (B stored [N][K]), bf16 in, fp32 acc ----------------
// m97 structure, BK=64 (R14: 103us / MfmaUtil 44%). + T1 XCD-swizzle: consecutive wgid share
// the A-panel and land on one XCD (nwg%8==0 -> simple bijection) -> A-panel L2-resident,
// B streams via L3. Targets the 111MB-vs-64MB over-fetch whose HBM-latency misses feed the
// per-iteration vmcnt(0) drain.
template <bool BF16_OUT>
__global__ __launch_bounds__(256, 4) void gemm_bt(
    const ushort* __restrict__ A, const ushort* __restrict__ B,
    void* __restrict__ Cp, int M, int N, int K) {
  __shared__ ushort a_lds[128 * 64];
  __shared__ ushort b_lds[128 * 64];
  const int tid = threadIdx.x;
  const int wid = tid >> 6, lane = tid & 63;
  const int l16 = lane & 15, lk = lane >> 4;
  const int wr = wid >> 1, wc = wid & 1;
  const int nx = gridDim.x;
  const int orig = blockIdx.y * nx + blockIdx.x;
  const int per = (nx * gridDim.y) >> 3;          // nwg divisible by 8 (768 / 512)
  const int wgid = (orig & 7) * per + (orig >> 3);
  const size_t a_row0 = (size_t)(wgid / nx) * 128;
  const size_t b_row0 = (size_t)(wgid % nx) * 128;

  f32x4 acc[4][4] = {};

  for (int kt = 0; kt < K; kt += 64) {
    __syncthreads();  // prior-iteration LDS reads complete before overwrite
#pragma unroll
    for (int i = 0; i < 4; ++i) {
      int c = i * 256 + tid;               // 1024 16B-chunks per tile (8 per 128B row)
      int row = c >> 3, pos = c & 7;
      int src = pos ^ (row & 7);           // involution: pre-swizzled source
      gload_lds16(A + (a_row0 + row) * K + kt + src * 8, &a_lds[c * 8]);
      gload_lds16(B + (b_row0 + row) * K + kt + src * 8, &b_lds[c * 8]);
    }
    __syncthreads();  // drains vmcnt: LDS tiles ready

#pragma unroll
    for (int kk = 0; kk < 2; ++kk) {
      bf16x8 af[4], bf[4];
#pragma unroll
      for (int m = 0; m < 4; ++m) {
        int row = wr * 64 + m * 16 + l16;
        int ch = (kk * 4 + lk) ^ (row & 7);
        af[m] = *reinterpret_cast<const bf16x8*>(&a_lds[row * 64 + ch * 8]);
      }
#pragma unroll
      for (int n = 0; n < 4; ++n) {
        int row = wc * 64 + n * 16 + l16;
        int ch = (kk * 4 + lk) ^ (row & 7);
        bf[n] = *reinterpret_cast<const bf16x8*>(&b_lds[row * 64 + ch * 8]);
      }
#pragma unroll
      for (int m = 0; m < 4; ++m)
#pragma unroll
        for (int n = 0; n < 4; ++n)
          acc[m][n] = __builtin_amdgcn_mfma_f32_16x16x32_bf16(af[m], bf[n], acc[m][n], 0, 0, 0);
    }
  }

#pragma unroll
  for (int m = 0; m < 4; ++m) {
    int row_b = wr * 64 + m * 16 + lk * 4;
#pragma unroll
    for (int n = 0; n < 4; ++n) {
      int col = (int)b_row0 + wc * 64 + n * 16 + l16;
#pragma unroll
      for (int r = 0; r < 4; ++r) {
        size_t row = a_row0 + row_b + r;
        if constexpr (BF16_OUT)
          ((ushort*)Cp)[row * N + col] = f2bf(acc[m][n][r]);
        else
          ((float*)Cp)[row * N + col] = acc[m][n][r];
      }
    }
  }
}

// ---------------- O-proj GEMM, K-split x2 in one launch (4 blocks/CU), BK=64 + XCD swizzle ----
__global__ __launch_bounds__(256, 4) void gemm_o_ks(
    const ushort* __restrict__ A, const ushort* __restrict__ B,
    float* __restrict__ P0, float* __restrict__ P1) {
  __shared__ ushort a_lds[128 * 64];
  __shared__ ushort b_lds[128 * 64];
  const int orig = blockIdx.x;                    // 1024 blocks
  const int wgid = (orig & 7) * 128 + (orig >> 3);
  const int kh = wgid >> 9;
  const int rem = wgid & 511;
  const size_t b_row0 = (size_t)(rem & 31) * 128;   // N/128 = 32
  const size_t a_row0 = (size_t)(rem >> 5) * 128;   // M/128 = 16
  const int k0 = kh * 2048, k1 = k0 + 2048;
  float* __restrict__ P = kh ? P1 : P0;
  const int tid = threadIdx.x;
  const int wid = tid >> 6, lane = tid & 63;
  const int l16 = lane & 15, lk = lane >> 4;
  const int wr = wid >> 1, wc = wid & 1;

  f32x4 acc[4][4] = {};

  for (int kt = k0; kt < k1; kt += 64) {
    __syncthreads();
#pragma unroll
    for (int i = 0; i < 4; ++i) {
      int c = i * 256 + tid;
      int row = c >> 3, pos = c & 7;
      int src = pos ^ (row & 7);
      gload_lds16(A + (a_row0 + row) * HID + kt + src * 8, &a_lds[c * 8]);
      gload_lds16(B + (b_row0 + row) * HID + kt + src * 8, &b_lds[c * 8]);
    }
    __syncthreads();

#pragma unroll
    for (int kk = 0; kk < 2; ++kk) {
      bf16x8 af[4], bf[4];
#pragma unroll
      for (int m = 0; m < 4; ++m) {
        int row = wr * 64 + m * 16 + l16;
        int ch = (kk * 4 + lk) ^ (row & 7);
        af[m] = *reinterpret_cast<const bf16x8*>(&a_lds[row * 64 + ch * 8]);
      }
#pragma unroll
      for (int n = 0; n < 4; ++n) {
        int row = wc * 64 + n * 16 + l16;
        int ch = (kk * 4 + lk) ^ (row & 7);
        bf[n] = *reinterpret_cast<const bf16x8*>(&b_lds[row * 64 + ch * 8]);
      }
#pragma unroll
      for (int m = 0; m < 4; ++m)
#pragma unroll
        for (int n = 0; n < 4; ++n)
          acc[m][n] = __builtin_amdgcn_mfma_f32_16x16x32_bf16(af[m], bf[n], acc[m][n], 0, 0, 0);
    }
  }

#pragma unroll
  for (int m = 0; m < 4; ++m) {
    int row_b = wr * 64 + m * 16 + lk * 4;
#pragma unroll
    for (int n = 0; n < 4; ++n) {
      int col = (int)b_row0 + wc * 64 + n * 16 + l16;
#pragma unroll
      for (int r = 0; r < 4; ++r)
        P[(a_row0 + row_b + r) * HID + col] = acc[m][n][r];
    }
  }
}

__global__ void add_f32(const float* __restrict__ a, const float* __restrict__ b,
                        float* __restrict__ o, int n) {
  int i = (blockIdx.x * 256 + threadIdx.x) * 4;
  if (i >= n) return;
  float4 x = *reinterpret_cast<const float4*>(a + i);
  float4 y = *reinterpret_cast<const float4*>(b + i);
  float4 z; z.x = x.x + y.x; z.y = x.y + y.y; z.z = x.z + y.z; z.w = x.w + y.w;
  *reinterpret_cast<float4*>(o + i) = z;
}

// ---------------- fused RoPE (Q/K cols) + V transpose — independent QKV regions ----------------
__global__ void rope_and_tv(ushort* __restrict__ QKV, ushort* __restrict__ Vt) {
  if (blockIdx.x < 2560) {
    int idx = blockIdx.x * 256 + threadIdx.x;  // 2048 * 40 * 8 threads
    int dg = idx & 7;
    int t = idx >> 3;
    int s = t / 40;
    int hh = t - s * 40;
    if (s >= S_LEN) return;
    int col = (hh < NH) ? hh * HD : HID + (hh - NH) * HD;
    ushort* base = QKV + (size_t)s * QKV_N + col + dg * 8;

    union U { uint4 v; ushort u[8]; };
    U L, H, OL, OH;
    L.v = *reinterpret_cast<const uint4*>(base);
    H.v = *reinterpret_cast<const uint4*>(base + 64);
    const float C0 = 13.287712379549449f / 64.0f;  // log2(10000)/64
#pragma unroll
    for (int j = 0; j < 8; ++j) {
      int d = dg * 8 + j;
      float invf = exp2f(-(float)d * C0);
      float ang = (float)s * invf;
      float sn, cs;
      sincosf(ang, &sn, &cs);
      float xl = bf2f(L.u[j]), xh = bf2f(H.u[j]);
      OL.u[j] = f2bf(xl * cs - xh * sn);
      OH.u[j] = f2bf(xh * cs + xl * sn);
    }
    *reinterpret_cast<uint4*>(base) = OL.v;
    *reinterpret_cast<uint4*>(base + 64) = OH.v;
  } else {
    __shared__ ushort t[64][65];
    int local = blockIdx.x - 2560;             // 32 s-tiles x 2 d-tiles x 8 hkv
    int s0 = (local & 31) * 64;
    int d0 = ((local >> 5) & 1) * 64;
    int hkv = local >> 6;
    int tx = threadIdx.x & 63, ty = threadIdx.x >> 6;  // 64 x 4
#pragma unroll
    for (int i = 0; i < 64; i += 4)
      t[i + ty][tx] = QKV[(size_t)(s0 + i + ty) * QKV_N + HID + NKV * HD + hkv * HD + d0 + tx];
    __syncthreads();
#pragma unroll
    for (int i = 0; i < 64; i += 4)
      Vt[((size_t)hkv * HD + d0 + i + ty) * S_LEN + s0 + tx] = t[tx][i + ty];
  }
}

// ---------------- flash attention: swapped-QK^T 32x32 MFMA, in-register softmax ----------------
// R8-proven. Grid = 256 blocks; h=(lin&7)*4+((lin>>3)&3), p=lin>>5; panels {p,15-p}
// sequentially -> uniform 34 KV-tiles; XCD-local KV (1MB per hkv fits 4MB XCD L2).
__global__ __launch_bounds__(256, 2) void attn_kernel(
    const ushort* __restrict__ QKV, const ushort* __restrict__ Vt, ushort* __restrict__ AO) {
  constexpr float SCALE = 0.08838834764831845f;  // 1/sqrt(128)
  __shared__ ushort k_lds[2][64 * 128];   // [krow][128 d], 16B chunks XOR-swizzled by (row&7)
  __shared__ ushort v_lds[2][128 * 64];   // [d][64 s], 16B chunks XOR-swizzled by (row&7)

  const int lin = blockIdx.x;
  const int h = ((lin & 7) << 2) + ((lin >> 3) & 3);
  const int p = lin >> 5;                 // 0..7
  const int hkv = h >> 2;
  const int tid = threadIdx.x, wid = tid >> 6, lane = tid & 63;
  const int l32 = lane & 31;
  const int hi = lane >> 5;

  auto stageKV = [&](int buf, int kt) {
#pragma unroll
    for (int i = 0; i < 4; ++i) {
      int c = i * 256 + wid * 64 + lane;
      int row = c >> 4, ch = c & 15;
      int sch = ch ^ (row & 7);
      gload_lds16(QKV + (size_t)(kt * 64 + row) * QKV_N + HID + hkv * HD + sch * 8,
                  &k_lds[buf][c * 8]);
    }
#pragma unroll
    for (int i = 0; i < 4; ++i) {
      int c = i * 256 + wid * 64 + lane;
      int row = c >> 3, ch = c & 7;
      int sch = ch ^ (row & 7);
      gload_lds16(Vt + ((size_t)hkv * HD + row) * S_LEN + (size_t)kt * 64 + sch * 8,
                  &v_lds[buf][c * 8]);
    }
  };

  for (int pi = 0; pi < 2; ++pi) {
    const int qb = pi ? (15 - p) : p;
    const int q0 = qb * 128;
    const int qg = q0 + wid * 32 + l32;   // this lane's q row

    bf16x8 qf[8];
    {
      const ushort* qrow = QKV + (size_t)qg * QKV_N + h * HD + hi * 8;
#pragma unroll
      for (int ds = 0; ds < 8; ++ds)
        qf[ds] = *reinterpret_cast<const bf16x8*>(qrow + ds * 16);
    }

    float m_run = -1e30f, l_run = 0.f;
    f32x16 oacc[4] = {};   // oacc[f][r] = O[q=l32][d = f*32 + crow(r,hi)]

    stageKV(0, 0);
    __syncthreads();

    const int nt = 2 * qb + 2;
    for (int kt = 0; kt < nt; ++kt) {
      const int cur = kt & 1;
      if (kt + 1 < nt) stageKV(cur ^ 1, kt + 1);

      if (kt * 64 <= q0 + wid * 32 + 31) {
        float pv[32];
        __builtin_amdgcn_s_setprio(1);
#pragma unroll
        for (int kf = 0; kf < 2; ++kf) {
          f32x16 s = {};
          int rk = kf * 32 + l32;
#pragma unroll
          for (int ds = 0; ds < 8; ++ds) {
            int c16 = (ds * 2 + hi) ^ (rk & 7);
            bf16x8 kfr = *reinterpret_cast<const bf16x8*>(&k_lds[cur][rk * 128 + c16 * 8]);
            s = __builtin_amdgcn_mfma_f32_32x32x16_bf16(kfr, qf[ds], s, 0, 0, 0);
          }
#pragma unroll
          for (int r = 0; r < 16; ++r) pv[kf * 16 + r] = s[r] * SCALE;
        }
        __builtin_amdgcn_s_setprio(0);

        if (kt * 64 + 63 > q0 + wid * 32) {  // diagonal tile: causal mask
#pragma unroll
          for (int kf = 0; kf < 2; ++kf)
#pragma unroll
            for (int r = 0; r < 16; ++r) {
              int kl = kf * 32 + (r & 3) + 8 * (r >> 2) + 4 * hi;
              if (kt * 64 + kl > qg) pv[kf * 16 + r] = -1e30f;
            }
        }

        float mt = pv[0];
#pragma unroll
        for (int i = 1; i < 32; ++i) mt = fmaxf(mt, pv[i]);
        mt = fmaxf(mt, __shfl_xor(mt, 32, 64));
        float mn = fmaxf(m_run, mt);
        float alpha = __expf(m_run - mn);
        float ls = 0.f;
#pragma unroll
        for (int i = 0; i < 32; ++i) { pv[i] = __expf(pv[i] - mn); ls += pv[i]; }
        ls += __shfl_xor(ls, 32, 64);
        l_run = l_run * alpha + ls;
        m_run = mn;
#pragma unroll
        for (int f = 0; f < 4; ++f)
#pragma unroll
          for (int r = 0; r < 16; ++r) oacc[f][r] *= alpha;

        // pack P -> PV B-operand (T12: cvt_pk + permlane32_swap)
        union PW { uint32_t w[4]; bf16x8 v; } pa[4];
#pragma unroll
        for (int ks = 0; ks < 4; ++ks) {
          uint32_t x0, x1, y0, y1;
          asm("v_cvt_pk_bf16_f32 %0, %1, %2" : "=v"(x0) : "v"(pv[8 * ks + 0]), "v"(pv[8 * ks + 1]));
          asm("v_cvt_pk_bf16_f32 %0, %1, %2" : "=v"(x1) : "v"(pv[8 * ks + 2]), "v"(pv[8 * ks + 3]));
          asm("v_cvt_pk_bf16_f32 %0, %1, %2" : "=v"(y0) : "v"(pv[8 * ks + 4]), "v"(pv[8 * ks + 5]));
          asm("v_cvt_pk_bf16_f32 %0, %1, %2" : "=v"(y1) : "v"(pv[8 * ks + 6]), "v"(pv[8 * ks + 7]));
          u32x2 r0 = __builtin_amdgcn_permlane32_swap(x0, y0, false, false);
          u32x2 r1 = __builtin_amdgcn_permlane32_swap(x1, y1, false, false);
          pa[ks].w[0] = r0.x; pa[ks].w[1] = r1.x; pa[ks].w[2] = r0.y; pa[ks].w[3] = r1.y;
        }

        __builtin_amdgcn_s_setprio(1);
#pragma unroll
        for (int ks = 0; ks < 4; ++ks) {
#pragma unroll
          for (int f = 0; f < 4; ++f) {
            int dv = f * 32 + l32;
            int c8 = (2 * ks + hi) ^ (dv & 7);
            bf16x8 vfr = *reinterpret_cast<const bf16x8*>(&v_lds[cur][dv * 64 + c8 * 8]);
            oacc[f] = __builtin_amdgcn_mfma_f32_32x32x16_bf16(vfr, pa[ks].v, oacc[f], 0, 0, 0);
          }
        }
        __builtin_amdgcn_s_setprio(0);
      }

      __syncthreads();
    }

    float inv_l = 1.0f / l_run;
    ushort* aorow = AO + (size_t)qg * HID + h * HD;
#pragma unroll
    for (int f = 0; f < 4; ++f)
#pragma unroll
      for (int g = 0; g < 4; ++g) {
        ushort4 o;
        o.x = f2bf(oacc[f][g * 4 + 0] * inv_l);
        o.y = f2bf(oacc[f][g * 4 + 1] * inv_l);
        o.z = f2bf(oacc[f][g * 4 + 2] * inv_l);
        o.w = f2bf(oacc[f][g * 4 + 3] * inv_l);
        *reinterpret_cast<ushort4*>(aorow + f * 32 + g * 8 + 4 * hi) = o;
      }
  }
}

// ---------------- launcher ----------------
extern "C" void kernel_launch(void* const* d_in, const int* in_sizes, int n_in,
                              void* d_out, int out_size, void* d_ws, size_t ws_size,
                              hipStream_t stream) {
  (void)in_sizes; (void)n_in; (void)out_size;
  const float* hs = (const float*)d_in[0];
  const float* Wq = (const float*)d_in[1];
  const float* Wk = (const float*)d_in[2];
  const float* Wv = (const float*)d_in[3];
  const float* Wo = (const float*)d_in[4];
  float* out = (float*)d_out;

  // workspace layout (bytes)
  char* ws = (char*)d_ws;
  const size_t OFF_HSB   = 0;                         // 2048*4096 bf16 = 16 MB
  const size_t OFF_WQKVT = OFF_HSB + 16777216;        // 6144*4096 bf16 = 48 MB
  const size_t OFF_WOT   = OFF_WQKVT + 50331648;      // 4096*4096 bf16 = 32 MB
  const size_t OFF_QKV   = OFF_WOT + 33554432;        // 2048*6144 bf16 = 24 MB
  const size_t OFF_VT    = OFF_QKV + 25165824;        // 8*128*2048 bf16 = 4 MB
  const size_t OFF_AO    = OFF_VT + 4194304;          // 2048*4096 bf16 = 16 MB
  if (ws_size < OFF_AO + 16777216) return;            // ~140 MB needed

  ushort* hsb   = (ushort*)(ws + OFF_HSB);
  ushort* WqkvT = (ushort*)(ws + OFF_WQKVT);
  ushort* WoT   = (ushort*)(ws + OFF_WOT);
  ushort* QKV   = (ushort*)(ws + OFF_QKV);
  ushort* Vt    = (ushort*)(ws + OFF_VT);
  ushort* AO    = (ushort*)(ws + OFF_AO);
  // f32 partials for the K-split O-proj, overlaid on hsb+WqkvT (both dead after QKV GEMM)
  float* P0 = (float*)(ws + 0);                       // 32 MB
  float* P1 = (float*)(ws + 33554432);                // 32 MB

  prep_all<<<18432, 256, 0, stream>>>(hs, Wq, Wk, Wv, Wo, hsb, WqkvT, WoT);
  gemm_bt<true><<<dim3(QKV_N / 128, S_LEN / 128), 256, 0, stream>>>(hsb, WqkvT, QKV, S_LEN, QKV_N, HID);
  rope_and_tv<<<3072, 256, 0, stream>>>(QKV, Vt);
  attn_kernel<<<256, 256, 0, stream>>>(QKV, Vt, AO);
  gemm_o_ks<<<1024, 256, 0, stream>>>(AO, WoT, P0, P1);
  add_f32<<<8192, 256, 0, stream>>>(P0, P1, out, S_LEN * HID);
}

// Round 16
// 327.052 us; speedup vs baseline: 1.0306x; 1.0306x over previous
//
#include <hip/hip_runtime.h>
#include <cstdint>
#include <cstddef>

typedef __attribute__((ext_vector_type(4))) float f32x4;
typedef __attribute__((ext_vector_type(16))) float f32x16;
typedef __attribute__((ext_vector_type(8))) short bf16x8;
typedef __attribute__((ext_vector_type(2))) unsigned int u32x2;

#define S_LEN   2048
#define HID     4096
#define NH      32
#define NKV     8
#define HD      128
#define QKV_N   6144   /* 4096 Q + 1024 K + 1024 V */

typedef const __attribute__((address_space(1))) unsigned int* gptr_t;
typedef __attribute__((address_space(3))) unsigned int* lptr_t;

__device__ __forceinline__ void gload_lds16(const void* g, void* l) {
  __builtin_amdgcn_global_load_lds((gptr_t)g, (lptr_t)l, 16, 0, 0);
}

__device__ __forceinline__ ushort f2bf(float f) {
  union { float f; uint32_t u; } v; v.f = f;
  uint32_t r = v.u + 0x7FFFu + ((v.u >> 16) & 1u);
  return (ushort)(r >> 16);
}
__device__ __forceinline__ float bf2f(ushort u) {
  union { uint32_t u; float f; } v; v.u = ((uint32_t)u) << 16;
  return v.f;
}

// ---------------- fused prep: hs cast + all 4 weight transposes (one launch) ----------------
// Blocks [0,8192): cast hs f32->bf16. Blocks [8192,18432): 64x64 transpose+cast tiles,
// float4 reads + ushort4 writes (G13). Near the ~46us BW floor for 288MB of traffic.
__global__ void prep_all(const float* __restrict__ hs,
                         const float* __restrict__ Wq, const float* __restrict__ Wk,
                         const float* __restrict__ Wv, const float* __restrict__ Wo,
                         ushort* __restrict__ hsb,
                         ushort* __restrict__ WqkvT, ushort* __restrict__ WoT) {
  int id = blockIdx.x;
  if (id < 8192) {
    int i = (id * 256 + (int)threadIdx.x) * 4;
    float4 v = *reinterpret_cast<const float4*>(hs + i);
    ushort4 o;
    o.x = f2bf(v.x); o.y = f2bf(v.y); o.z = f2bf(v.z); o.w = f2bf(v.w);
    *reinterpret_cast<ushort4*>(hsb + i) = o;
    return;
  }
  __shared__ float t[64][69];   // pad 69: read side (row=4*tx+j, col fixed) is 2-way = free
  id -= 8192;
  const float* src; ushort* dst; int C, local;
  if (id < 4096)        { src = Wq; dst = WqkvT;                      C = 4096; local = id; }
  else if (id < 5120)   { src = Wk; dst = WqkvT + (size_t)4096 * HID; C = 1024; local = id - 4096; }
  else if (id < 6144)   { src = Wv; dst = WqkvT + (size_t)5120 * HID; C = 1024; local = id - 5120; }
  else                  { src = Wo; dst = WoT;                        C = 4096; local = id - 6144; }
  const int cb = C >> 6;
  int bx = local % cb, by = local / cb;
  int tx = threadIdx.x & 15, ty = threadIdx.x >> 4;  // 16 x 16
  int r0 = by * 64, c0 = bx * 64;
#pragma unroll
  for (int i = 0; i < 4; ++i) {
    float4 v = *reinterpret_cast<const float4*>(&src[(size_t)(r0 + ty + i * 16) * C + c0 + tx * 4]);
    t[ty + i * 16][tx * 4 + 0] = v.x;
    t[ty + i * 16][tx * 4 + 1] = v.y;
    t[ty + i * 16][tx * 4 + 2] = v.z;
    t[ty + i * 16][tx * 4 + 3] = v.w;
  }
  __syncthreads();
#pragma unroll
  for (int i = 0; i < 4; ++i) {
    int cc = ty + i * 16;
    ushort4 o;
    o.x = f2bf(t[tx * 4 + 0][cc]);
    o.y = f2bf(t[tx * 4 + 1][cc]);
    o.z = f2bf(t[tx * 4 + 2][cc]);
    o.w = f2bf(t[tx * 4 + 3][cc]);
    *reinterpret_cast<ushort4*>(&dst[(size_t)(c0 + cc) * 4096 + r0 + tx * 4]) = o;
  }
}

// ---------------- GEMM: C[M][N] = A[M][K] * B^T  (B stored [N][K]), bf16 in, fp32 acc ----------------
// m97 structure, BK=64 (R14-measured: 103us / MfmaUtil 44% / VGPR 60). NO XCD swizzle:
// R15 measured it at -12us here (L3-fit regime; default round-robin already gives each
// XCD L2-resident B-panels since B-col c always lands on XCD c%8).
template <bool BF16_OUT>
__global__ __launch_bounds__(256, 4) void gemm_bt(
    const ushort* __restrict__ A, const ushort* __restrict__ B,
    void* __restrict__ Cp, int M, int N, int K) {
  __shared__ ushort a_lds[128 * 64];
  __shared__ ushort b_lds[128 * 64];
  const int tid = threadIdx.x;
  const int wid = tid >> 6, lane = tid & 63;
  const int l16 = lane & 15, lk = lane >> 4;
  const int wr = wid >> 1, wc = wid & 1;
  const size_t a_row0 = (size_t)blockIdx.y * 128;
  const size_t b_row0 = (size_t)blockIdx.x * 128;

  f32x4 acc[4][4] = {};

  for (int kt = 0; kt < K; kt += 64) {
    __syncthreads();  // prior-iteration LDS reads complete before overwrite
#pragma unroll
    for (int i = 0; i < 4; ++i) {
      int c = i * 256 + tid;               // 1024 16B-chunks per tile (8 per 128B row)
      int row = c >> 3, pos = c & 7;
      int src = pos ^ (row & 7);           // involution: pre-swizzled source
      gload_lds16(A + (a_row0 + row) * K + kt + src * 8, &a_lds[c * 8]);
      gload_lds16(B + (b_row0 + row) * K + kt + src * 8, &b_lds[c * 8]);
    }
    __syncthreads();  // drains vmcnt: LDS tiles ready

#pragma unroll
    for (int kk = 0; kk < 2; ++kk) {
      bf16x8 af[4], bf[4];
#pragma unroll
      for (int m = 0; m < 4; ++m) {
        int row = wr * 64 + m * 16 + l16;
        int ch = (kk * 4 + lk) ^ (row & 7);
        af[m] = *reinterpret_cast<const bf16x8*>(&a_lds[row * 64 + ch * 8]);
      }
#pragma unroll
      for (int n = 0; n < 4; ++n) {
        int row = wc * 64 + n * 16 + l16;
        int ch = (kk * 4 + lk) ^ (row & 7);
        bf[n] = *reinterpret_cast<const bf16x8*>(&b_lds[row * 64 + ch * 8]);
      }
#pragma unroll
      for (int m = 0; m < 4; ++m)
#pragma unroll
        for (int n = 0; n < 4; ++n)
          acc[m][n] = __builtin_amdgcn_mfma_f32_16x16x32_bf16(af[m], bf[n], acc[m][n], 0, 0, 0);
    }
  }

#pragma unroll
  for (int m = 0; m < 4; ++m) {
    int row_b = wr * 64 + m * 16 + lk * 4;
#pragma unroll
    for (int n = 0; n < 4; ++n) {
      int col = (int)b_row0 + wc * 64 + n * 16 + l16;
#pragma unroll
      for (int r = 0; r < 4; ++r) {
        size_t row = a_row0 + row_b + r;
        if constexpr (BF16_OUT)
          ((ushort*)Cp)[row * N + col] = f2bf(acc[m][n][r]);
        else
          ((float*)Cp)[row * N + col] = acc[m][n][r];
      }
    }
  }
}

// ---------------- O-proj GEMM, K-split x2 in one launch (4 blocks/CU), BK=64 ----------------
// (No XCD swizzle — same R15 lesson.)
__global__ __launch_bounds__(256, 4) void gemm_o_ks(
    const ushort* __restrict__ A, const ushort* __restrict__ B,
    float* __restrict__ P0, float* __restrict__ P1) {
  __shared__ ushort a_lds[128 * 64];
  __shared__ ushort b_lds[128 * 64];
  const int bid = blockIdx.x;
  const int kh = bid >> 9;
  const int rem = bid & 511;
  const size_t b_row0 = (size_t)(rem & 31) * 128;   // N/128 = 32
  const size_t a_row0 = (size_t)(rem >> 5) * 128;   // M/128 = 16
  const int k0 = kh * 2048, k1 = k0 + 2048;
  float* __restrict__ P = kh ? P1 : P0;
  const int tid = threadIdx.x;
  const int wid = tid >> 6, lane = tid & 63;
  const int l16 = lane & 15, lk = lane >> 4;
  const int wr = wid >> 1, wc = wid & 1;

  f32x4 acc[4][4] = {};

  for (int kt = k0; kt < k1; kt += 64) {
    __syncthreads();
#pragma unroll
    for (int i = 0; i < 4; ++i) {
      int c = i * 256 + tid;
      int row = c >> 3, pos = c & 7;
      int src = pos ^ (row & 7);
      gload_lds16(A + (a_row0 + row) * HID + kt + src * 8, &a_lds[c * 8]);
      gload_lds16(B + (b_row0 + row) * HID + kt + src * 8, &b_lds[c * 8]);
    }
    __syncthreads();

#pragma unroll
    for (int kk = 0; kk < 2; ++kk) {
      bf16x8 af[4], bf[4];
#pragma unroll
      for (int m = 0; m < 4; ++m) {
        int row = wr * 64 + m * 16 + l16;
        int ch = (kk * 4 + lk) ^ (row & 7);
        af[m] = *reinterpret_cast<const bf16x8*>(&a_lds[row * 64 + ch * 8]);
      }
#pragma unroll
      for (int n = 0; n < 4; ++n) {
        int row = wc * 64 + n * 16 + l16;
        int ch = (kk * 4 + lk) ^ (row & 7);
        bf[n] = *reinterpret_cast<const bf16x8*>(&b_lds[row * 64 + ch * 8]);
      }
#pragma unroll
      for (int m = 0; m < 4; ++m)
#pragma unroll
        for (int n = 0; n < 4; ++n)
          acc[m][n] = __builtin_amdgcn_mfma_f32_16x16x32_bf16(af[m], bf[n], acc[m][n], 0, 0, 0);
    }
  }

#pragma unroll
  for (int m = 0; m < 4; ++m) {
    int row_b = wr * 64 + m * 16 + lk * 4;
#pragma unroll
    for (int n = 0; n < 4; ++n) {
      int col = (int)b_row0 + wc * 64 + n * 16 + l16;
#pragma unroll
      for (int r = 0; r < 4; ++r)
        P[(a_row0 + row_b + r) * HID + col] = acc[m][n][r];
    }
  }
}

__global__ void add_f32(const float* __restrict__ a, const float* __restrict__ b,
                        float* __restrict__ o, int n) {
  int i = (blockIdx.x * 256 + threadIdx.x) * 4;
  if (i >= n) return;
  float4 x = *reinterpret_cast<const float4*>(a + i);
  float4 y = *reinterpret_cast<const float4*>(b + i);
  float4 z; z.x = x.x + y.x; z.y = x.y + y.y; z.z = x.z + y.z; z.w = x.w + y.w;
  *reinterpret_cast<float4*>(o + i) = z;
}

// ---------------- fused RoPE (Q/K cols) + V transpose — independent QKV regions ----------------
__global__ void rope_and_tv(ushort* __restrict__ QKV, ushort* __restrict__ Vt) {
  if (blockIdx.x < 2560) {
    int idx = blockIdx.x * 256 + threadIdx.x;  // 2048 * 40 * 8 threads
    int dg = idx & 7;
    int t = idx >> 3;
    int s = t / 40;
    int hh = t - s * 40;
    if (s >= S_LEN) return;
    int col = (hh < NH) ? hh * HD : HID + (hh - NH) * HD;
    ushort* base = QKV + (size_t)s * QKV_N + col + dg * 8;

    union U { uint4 v; ushort u[8]; };
    U L, H, OL, OH;
    L.v = *reinterpret_cast<const uint4*>(base);
    H.v = *reinterpret_cast<const uint4*>(base + 64);
    const float C0 = 13.287712379549449f / 64.0f;  // log2(10000)/64
#pragma unroll
    for (int j = 0; j < 8; ++j) {
      int d = dg * 8 + j;
      float invf = exp2f(-(float)d * C0);
      float ang = (float)s * invf;
      float sn, cs;
      sincosf(ang, &sn, &cs);
      float xl = bf2f(L.u[j]), xh = bf2f(H.u[j]);
      OL.u[j] = f2bf(xl * cs - xh * sn);
      OH.u[j] = f2bf(xh * cs + xl * sn);
    }
    *reinterpret_cast<uint4*>(base) = OL.v;
    *reinterpret_cast<uint4*>(base + 64) = OH.v;
  } else {
    __shared__ ushort t[64][65];
    int local = blockIdx.x - 2560;             // 32 s-tiles x 2 d-tiles x 8 hkv
    int s0 = (local & 31) * 64;
    int d0 = ((local >> 5) & 1) * 64;
    int hkv = local >> 6;
    int tx = threadIdx.x & 63, ty = threadIdx.x >> 6;  // 64 x 4
#pragma unroll
    for (int i = 0; i < 64; i += 4)
      t[i + ty][tx] = QKV[(size_t)(s0 + i + ty) * QKV_N + HID + NKV * HD + hkv * HD + d0 + tx];
    __syncthreads();
#pragma unroll
    for (int i = 0; i < 64; i += 4)
      Vt[((size_t)hkv * HD + d0 + i + ty) * S_LEN + s0 + tx] = t[tx][i + ty];
  }
}

// ---------------- flash attention: swapped-QK^T 32x32 MFMA, in-register softmax ----------------
// R8-proven. Grid = 256 blocks; h=(lin&7)*4+((lin>>3)&3), p=lin>>5; panels {p,15-p}
// sequentially -> uniform 34 KV-tiles; XCD-local KV (1MB per hkv fits 4MB XCD L2).
__global__ __launch_bounds__(256, 2) void attn_kernel(
    const ushort* __restrict__ QKV, const ushort* __restrict__ Vt, ushort* __restrict__ AO) {
  constexpr float SCALE = 0.08838834764831845f;  // 1/sqrt(128)
  __shared__ ushort k_lds[2][64 * 128];   // [krow][128 d], 16B chunks XOR-swizzled by (row&7)
  __shared__ ushort v_lds[2][128 * 64];   // [d][64 s], 16B chunks XOR-swizzled by (row&7)

  const int lin = blockIdx.x;
  const int h = ((lin & 7) << 2) + ((lin >> 3) & 3);
  const int p = lin >> 5;                 // 0..7
  const int hkv = h >> 2;
  const int tid = threadIdx.x, wid = tid >> 6, lane = tid & 63;
  const int l32 = lane & 31;
  const int hi = lane >> 5;

  auto stageKV = [&](int buf, int kt) {
#pragma unroll
    for (int i = 0; i < 4; ++i) {
      int c = i * 256 + wid * 64 + lane;
      int row = c >> 4, ch = c & 15;
      int sch = ch ^ (row & 7);
      gload_lds16(QKV + (size_t)(kt * 64 + row) * QKV_N + HID + hkv * HD + sch * 8,
                  &k_lds[buf][c * 8]);
    }
#pragma unroll
    for (int i = 0; i < 4; ++i) {
      int c = i * 256 + wid * 64 + lane;
      int row = c >> 3, ch = c & 7;
      int sch = ch ^ (row & 7);
      gload_lds16(Vt + ((size_t)hkv * HD + row) * S_LEN + (size_t)kt * 64 + sch * 8,
                  &v_lds[buf][c * 8]);
    }
  };

  for (int pi = 0; pi < 2; ++pi) {
    const int qb = pi ? (15 - p) : p;
    const int q0 = qb * 128;
    const int qg = q0 + wid * 32 + l32;   // this lane's q row

    bf16x8 qf[8];
    {
      const ushort* qrow = QKV + (size_t)qg * QKV_N + h * HD + hi * 8;
#pragma unroll
      for (int ds = 0; ds < 8; ++ds)
        qf[ds] = *reinterpret_cast<const bf16x8*>(qrow + ds * 16);
    }

    float m_run = -1e30f, l_run = 0.f;
    f32x16 oacc[4] = {};   // oacc[f][r] = O[q=l32][d = f*32 + crow(r,hi)]

    stageKV(0, 0);
    __syncthreads();

    const int nt = 2 * qb + 2;
    for (int kt = 0; kt < nt; ++kt) {
      const int cur = kt & 1;
      if (kt + 1 < nt) stageKV(cur ^ 1, kt + 1);

      if (kt * 64 <= q0 + wid * 32 + 31) {
        float pv[32];
        __builtin_amdgcn_s_setprio(1);
#pragma unroll
        for (int kf = 0; kf < 2; ++kf) {
          f32x16 s = {};
          int rk = kf * 32 + l32;
#pragma unroll
          for (int ds = 0; ds < 8; ++ds) {
            int c16 = (ds * 2 + hi) ^ (rk & 7);
            bf16x8 kfr = *reinterpret_cast<const bf16x8*>(&k_lds[cur][rk * 128 + c16 * 8]);
            s = __builtin_amdgcn_mfma_f32_32x32x16_bf16(kfr, qf[ds], s, 0, 0, 0);
          }
#pragma unroll
          for (int r = 0; r < 16; ++r) pv[kf * 16 + r] = s[r] * SCALE;
        }
        __builtin_amdgcn_s_setprio(0);

        if (kt * 64 + 63 > q0 + wid * 32) {  // diagonal tile: causal mask
#pragma unroll
          for (int kf = 0; kf < 2; ++kf)
#pragma unroll
            for (int r = 0; r < 16; ++r) {
              int kl = kf * 32 + (r & 3) + 8 * (r >> 2) + 4 * hi;
              if (kt * 64 + kl > qg) pv[kf * 16 + r] = -1e30f;
            }
        }

        float mt = pv[0];
#pragma unroll
        for (int i = 1; i < 32; ++i) mt = fmaxf(mt, pv[i]);
        mt = fmaxf(mt, __shfl_xor(mt, 32, 64));
        float mn = fmaxf(m_run, mt);
        float alpha = __expf(m_run - mn);
        float ls = 0.f;
#pragma unroll
        for (int i = 0; i < 32; ++i) { pv[i] = __expf(pv[i] - mn); ls += pv[i]; }
        ls += __shfl_xor(ls, 32, 64);
        l_run = l_run * alpha + ls;
        m_run = mn;
#pragma unroll
        for (int f = 0; f < 4; ++f)
#pragma unroll
          for (int r = 0; r < 16; ++r) oacc[f][r] *= alpha;

        // pack P -> PV B-operand (T12: cvt_pk + permlane32_swap)
        union PW { uint32_t w[4]; bf16x8 v; } pa[4];
#pragma unroll
        for (int ks = 0; ks < 4; ++ks) {
          uint32_t x0, x1, y0, y1;
          asm("v_cvt_pk_bf16_f32 %0, %1, %2" : "=v"(x0) : "v"(pv[8 * ks + 0]), "v"(pv[8 * ks + 1]));
          asm("v_cvt_pk_bf16_f32 %0, %1, %2" : "=v"(x1) : "v"(pv[8 * ks + 2]), "v"(pv[8 * ks + 3]));
          asm("v_cvt_pk_bf16_f32 %0, %1, %2" : "=v"(y0) : "v"(pv[8 * ks + 4]), "v"(pv[8 * ks + 5]));
          asm("v_cvt_pk_bf16_f32 %0, %1, %2" : "=v"(y1) : "v"(pv[8 * ks + 6]), "v"(pv[8 * ks + 7]));
          u32x2 r0 = __builtin_amdgcn_permlane32_swap(x0, y0, false, false);
          u32x2 r1 = __builtin_amdgcn_permlane32_swap(x1, y1, false, false);
          pa[ks].w[0] = r0.x; pa[ks].w[1] = r1.x; pa[ks].w[2] = r0.y; pa[ks].w[3] = r1.y;
        }

        __builtin_amdgcn_s_setprio(1);
#pragma unroll
        for (int ks = 0; ks < 4; ++ks) {
#pragma unroll
          for (int f = 0; f < 4; ++f) {
            int dv = f * 32 + l32;
            int c8 = (2 * ks + hi) ^ (dv & 7);
            bf16x8 vfr = *reinterpret_cast<const bf16x8*>(&v_lds[cur][dv * 64 + c8 * 8]);
            oacc[f] = __builtin_amdgcn_mfma_f32_32x32x16_bf16(vfr, pa[ks].v, oacc[f], 0, 0, 0);
          }
        }
        __builtin_amdgcn_s_setprio(0);
      }

      __syncthreads();
    }

    float inv_l = 1.0f / l_run;
    ushort* aorow = AO + (size_t)qg * HID + h * HD;
#pragma unroll
    for (int f = 0; f < 4; ++f)
#pragma unroll
      for (int g = 0; g < 4; ++g) {
        ushort4 o;
        o.x = f2bf(oacc[f][g * 4 + 0] * inv_l);
        o.y = f2bf(oacc[f][g * 4 + 1] * inv_l);
        o.z = f2bf(oacc[f][g * 4 + 2] * inv_l);
        o.w = f2bf(oacc[f][g * 4 + 3] * inv_l);
        *reinterpret_cast<ushort4*>(aorow + f * 32 + g * 8 + 4 * hi) = o;
      }
  }
}

// ---------------- launcher ----------------
extern "C" void kernel_launch(void* const* d_in, const int* in_sizes, int n_in,
                              void* d_out, int out_size, void* d_ws, size_t ws_size,
                              hipStream_t stream) {
  (void)in_sizes; (void)n_in; (void)out_size;
  const float* hs = (const float*)d_in[0];
  const float* Wq = (const float*)d_in[1];
  const float* Wk = (const float*)d_in[2];
  const float* Wv = (const float*)d_in[3];
  const float* Wo = (const float*)d_in[4];
  float* out = (float*)d_out;

  // workspace layout (bytes)
  char* ws = (char*)d_ws;
  const size_t OFF_HSB   = 0;                         // 2048*4096 bf16 = 16 MB
  const size_t OFF_WQKVT = OFF_HSB + 16777216;        // 6144*4096 bf16 = 48 MB
  const size_t OFF_WOT   = OFF_WQKVT + 50331648;      // 4096*4096 bf16 = 32 MB
  const size_t OFF_QKV   = OFF_WOT + 33554432;        // 2048*6144 bf16 = 24 MB
  const size_t OFF_VT    = OFF_QKV + 25165824;        // 8*128*2048 bf16 = 4 MB
  const size_t OFF_AO    = OFF_VT + 4194304;          // 2048*4096 bf16 = 16 MB
  if (ws_size < OFF_AO + 16777216) return;            // ~140 MB needed

  ushort* hsb   = (ushort*)(ws + OFF_HSB);
  ushort* WqkvT = (ushort*)(ws + OFF_WQKVT);
  ushort* WoT   = (ushort*)(ws + OFF_WOT);
  ushort* QKV   = (ushort*)(ws + OFF_QKV);
  ushort* Vt    = (ushort*)(ws + OFF_VT);
  ushort* AO    = (ushort*)(ws + OFF_AO);
  // f32 partials for the K-split O-proj, overlaid on hsb+WqkvT (both dead after QKV GEMM)
  float* P0 = (float*)(ws + 0);                       // 32 MB
  float* P1 = (float*)(ws + 33554432);                // 32 MB

  prep_all<<<18432, 256, 0, stream>>>(hs, Wq, Wk, Wv, Wo, hsb, WqkvT, WoT);
  gemm_bt<true><<<dim3(QKV_N / 128, S_LEN / 128), 256, 0, stream>>>(hsb, WqkvT, QKV, S_LEN, QKV_N, HID);
  rope_and_tv<<<3072, 256, 0, stream>>>(QKV, Vt);
  attn_kernel<<<256, 256, 0, stream>>>(QKV, Vt, AO);
  gemm_o_ks<<<1024, 256, 0, stream>>>(AO, WoT, P0, P1);
  add_f32<<<8192, 256, 0, stream>>>(P0, P1, out, S_LEN * HID);
}

// Round 17
// 321.931 us; speedup vs baseline: 1.0470x; 1.0159x over previous
//
#include <hip/hip_runtime.h>
#include <cstdint>
#include <cstddef>

typedef __attribute__((ext_vector_type(4))) float f32x4;
typedef __attribute__((ext_vector_type(16))) float f32x16;
typedef __attribute__((ext_vector_type(8))) short bf16x8;
typedef __attribute__((ext_vector_type(2))) unsigned int u32x2;

#define S_LEN   2048
#define HID     4096
#define NH      32
#define NKV     8
#define HD      128
#define QKV_N   6144   /* 4096 Q + 1024 K + 1024 V */

typedef const __attribute__((address_space(1))) unsigned int* gptr_t;
typedef __attribute__((address_space(3))) unsigned int* lptr_t;

__device__ __forceinline__ void gload_lds16(const void* g, void* l) {
  __builtin_amdgcn_global_load_lds((gptr_t)g, (lptr_t)l, 16, 0, 0);
}

__device__ __forceinline__ ushort f2bf(float f) {
  union { float f; uint32_t u; } v; v.f = f;
  uint32_t r = v.u + 0x7FFFu + ((v.u >> 16) & 1u);
  return (ushort)(r >> 16);
}
__device__ __forceinline__ float bf2f(ushort u) {
  union { uint32_t u; float f; } v; v.u = ((uint32_t)u) << 16;
  return v.f;
}

// ---------------- fused prep: hs cast + all 4 weight transposes (one launch) ----------------
__global__ void prep_all(const float* __restrict__ hs,
                         const float* __restrict__ Wq, const float* __restrict__ Wk,
                         const float* __restrict__ Wv, const float* __restrict__ Wo,
                         ushort* __restrict__ hsb,
                         ushort* __restrict__ WqkvT, ushort* __restrict__ WoT) {
  int id = blockIdx.x;
  if (id < 8192) {
    int i = (id * 256 + (int)threadIdx.x) * 4;
    float4 v = *reinterpret_cast<const float4*>(hs + i);
    ushort4 o;
    o.x = f2bf(v.x); o.y = f2bf(v.y); o.z = f2bf(v.z); o.w = f2bf(v.w);
    *reinterpret_cast<ushort4*>(hsb + i) = o;
    return;
  }
  __shared__ float t[64][69];   // pad 69: read side (row=4*tx+j, col fixed) is 2-way = free
  id -= 8192;
  const float* src; ushort* dst; int C, local;
  if (id < 4096)        { src = Wq; dst = WqkvT;                      C = 4096; local = id; }
  else if (id < 5120)   { src = Wk; dst = WqkvT + (size_t)4096 * HID; C = 1024; local = id - 4096; }
  else if (id < 6144)   { src = Wv; dst = WqkvT + (size_t)5120 * HID; C = 1024; local = id - 5120; }
  else                  { src = Wo; dst = WoT;                        C = 4096; local = id - 6144; }
  const int cb = C >> 6;
  int bx = local % cb, by = local / cb;
  int tx = threadIdx.x & 15, ty = threadIdx.x >> 4;  // 16 x 16
  int r0 = by * 64, c0 = bx * 64;
#pragma unroll
  for (int i = 0; i < 4; ++i) {
    float4 v = *reinterpret_cast<const float4*>(&src[(size_t)(r0 + ty + i * 16) * C + c0 + tx * 4]);
    t[ty + i * 16][tx * 4 + 0] = v.x;
    t[ty + i * 16][tx * 4 + 1] = v.y;
    t[ty + i * 16][tx * 4 + 2] = v.z;
    t[ty + i * 16][tx * 4 + 3] = v.w;
  }
  __syncthreads();
#pragma unroll
  for (int i = 0; i < 4; ++i) {
    int cc = ty + i * 16;
    ushort4 o;
    o.x = f2bf(t[tx * 4 + 0][cc]);
    o.y = f2bf(t[tx * 4 + 1][cc]);
    o.z = f2bf(t[tx * 4 + 2][cc]);
    o.w = f2bf(t[tx * 4 + 3][cc]);
    *reinterpret_cast<ushort4*>(&dst[(size_t)(c0 + cc) * 4096 + r0 + tx * 4]) = o;
  }
}

// ---------------- GEMM: C[M][N] = A[M][K] * B^T  (B stored [N][K]), bf16 in, fp32 acc ----------------
// m97 structure, BK=64 (R14/R16-measured: 103-112us / MfmaUtil 39-44%). No XCD swizzle
// (R15: -12us in this L3-fit regime).
template <bool BF16_OUT>
__global__ __launch_bounds__(256, 4) void gemm_bt(
    const ushort* __restrict__ A, const ushort* __restrict__ B,
    void* __restrict__ Cp, int M, int N, int K) {
  __shared__ ushort a_lds[128 * 64];
  __shared__ ushort b_lds[128 * 64];
  const int tid = threadIdx.x;
  const int wid = tid >> 6, lane = tid & 63;
  const int l16 = lane & 15, lk = lane >> 4;
  const int wr = wid >> 1, wc = wid & 1;
  const size_t a_row0 = (size_t)blockIdx.y * 128;
  const size_t b_row0 = (size_t)blockIdx.x * 128;

  f32x4 acc[4][4] = {};

  for (int kt = 0; kt < K; kt += 64) {
    __syncthreads();  // prior-iteration LDS reads complete before overwrite
#pragma unroll
    for (int i = 0; i < 4; ++i) {
      int c = i * 256 + tid;               // 1024 16B-chunks per tile (8 per 128B row)
      int row = c >> 3, pos = c & 7;
      int src = pos ^ (row & 7);           // involution: pre-swizzled source
      gload_lds16(A + (a_row0 + row) * K + kt + src * 8, &a_lds[c * 8]);
      gload_lds16(B + (b_row0 + row) * K + kt + src * 8, &b_lds[c * 8]);
    }
    __syncthreads();  // drains vmcnt: LDS tiles ready

#pragma unroll
    for (int kk = 0; kk < 2; ++kk) {
      bf16x8 af[4], bf[4];
#pragma unroll
      for (int m = 0; m < 4; ++m) {
        int row = wr * 64 + m * 16 + l16;
        int ch = (kk * 4 + lk) ^ (row & 7);
        af[m] = *reinterpret_cast<const bf16x8*>(&a_lds[row * 64 + ch * 8]);
      }
#pragma unroll
      for (int n = 0; n < 4; ++n) {
        int row = wc * 64 + n * 16 + l16;
        int ch = (kk * 4 + lk) ^ (row & 7);
        bf[n] = *reinterpret_cast<const bf16x8*>(&b_lds[row * 64 + ch * 8]);
      }
#pragma unroll
      for (int m = 0; m < 4; ++m)
#pragma unroll
        for (int n = 0; n < 4; ++n)
          acc[m][n] = __builtin_amdgcn_mfma_f32_16x16x32_bf16(af[m], bf[n], acc[m][n], 0, 0, 0);
    }
  }

#pragma unroll
  for (int m = 0; m < 4; ++m) {
    int row_b = wr * 64 + m * 16 + lk * 4;
#pragma unroll
    for (int n = 0; n < 4; ++n) {
      int col = (int)b_row0 + wc * 64 + n * 16 + l16;
#pragma unroll
      for (int r = 0; r < 4; ++r) {
        size_t row = a_row0 + row_b + r;
        if constexpr (BF16_OUT)
          ((ushort*)Cp)[row * N + col] = f2bf(acc[m][n][r]);
        else
          ((float*)Cp)[row * N + col] = acc[m][n][r];
      }
    }
  }
}

// ---------------- O-proj GEMM, K-split x2 in one launch (4 blocks/CU), BK=64 ----------------
__global__ __launch_bounds__(256, 4) void gemm_o_ks(
    const ushort* __restrict__ A, const ushort* __restrict__ B,
    float* __restrict__ P0, float* __restrict__ P1) {
  __shared__ ushort a_lds[128 * 64];
  __shared__ ushort b_lds[128 * 64];
  const int bid = blockIdx.x;
  const int kh = bid >> 9;
  const int rem = bid & 511;
  const size_t b_row0 = (size_t)(rem & 31) * 128;   // N/128 = 32
  const size_t a_row0 = (size_t)(rem >> 5) * 128;   // M/128 = 16
  const int k0 = kh * 2048, k1 = k0 + 2048;
  float* __restrict__ P = kh ? P1 : P0;
  const int tid = threadIdx.x;
  const int wid = tid >> 6, lane = tid & 63;
  const int l16 = lane & 15, lk = lane >> 4;
  const int wr = wid >> 1, wc = wid & 1;

  f32x4 acc[4][4] = {};

  for (int kt = k0; kt < k1; kt += 64) {
    __syncthreads();
#pragma unroll
    for (int i = 0; i < 4; ++i) {
      int c = i * 256 + tid;
      int row = c >> 3, pos = c & 7;
      int src = pos ^ (row & 7);
      gload_lds16(A + (a_row0 + row) * HID + kt + src * 8, &a_lds[c * 8]);
      gload_lds16(B + (b_row0 + row) * HID + kt + src * 8, &b_lds[c * 8]);
    }
    __syncthreads();

#pragma unroll
    for (int kk = 0; kk < 2; ++kk) {
      bf16x8 af[4], bf[4];
#pragma unroll
      for (int m = 0; m < 4; ++m) {
        int row = wr * 64 + m * 16 + l16;
        int ch = (kk * 4 + lk) ^ (row & 7);
        af[m] = *reinterpret_cast<const bf16x8*>(&a_lds[row * 64 + ch * 8]);
      }
#pragma unroll
      for (int n = 0; n < 4; ++n) {
        int row = wc * 64 + n * 16 + l16;
        int ch = (kk * 4 + lk) ^ (row & 7);
        bf[n] = *reinterpret_cast<const bf16x8*>(&b_lds[row * 64 + ch * 8]);
      }
#pragma unroll
      for (int m = 0; m < 4; ++m)
#pragma unroll
        for (int n = 0; n < 4; ++n)
          acc[m][n] = __builtin_amdgcn_mfma_f32_16x16x32_bf16(af[m], bf[n], acc[m][n], 0, 0, 0);
    }
  }

#pragma unroll
  for (int m = 0; m < 4; ++m) {
    int row_b = wr * 64 + m * 16 + lk * 4;
#pragma unroll
    for (int n = 0; n < 4; ++n) {
      int col = (int)b_row0 + wc * 64 + n * 16 + l16;
#pragma unroll
      for (int r = 0; r < 4; ++r)
        P[(a_row0 + row_b + r) * HID + col] = acc[m][n][r];
    }
  }
}

__global__ void add_f32(const float* __restrict__ a, const float* __restrict__ b,
                        float* __restrict__ o, int n) {
  int i = (blockIdx.x * 256 + threadIdx.x) * 4;
  if (i >= n) return;
  float4 x = *reinterpret_cast<const float4*>(a + i);
  float4 y = *reinterpret_cast<const float4*>(b + i);
  float4 z; z.x = x.x + y.x; z.y = x.y + y.y; z.z = x.z + y.z; z.w = x.w + y.w;
  *reinterpret_cast<float4*>(o + i) = z;
}

// ---------------- fused RoPE (Q/K cols) + V transpose — independent QKV regions ----------------
__global__ void rope_and_tv(ushort* __restrict__ QKV, ushort* __restrict__ Vt) {
  if (blockIdx.x < 2560) {
    int idx = blockIdx.x * 256 + threadIdx.x;  // 2048 * 40 * 8 threads
    int dg = idx & 7;
    int t = idx >> 3;
    int s = t / 40;
    int hh = t - s * 40;
    if (s >= S_LEN) return;
    int col = (hh < NH) ? hh * HD : HID + (hh - NH) * HD;
    ushort* base = QKV + (size_t)s * QKV_N + col + dg * 8;

    union U { uint4 v; ushort u[8]; };
    U L, H, OL, OH;
    L.v = *reinterpret_cast<const uint4*>(base);
    H.v = *reinterpret_cast<const uint4*>(base + 64);
    const float C0 = 13.287712379549449f / 64.0f;  // log2(10000)/64
#pragma unroll
    for (int j = 0; j < 8; ++j) {
      int d = dg * 8 + j;
      float invf = exp2f(-(float)d * C0);
      float ang = (float)s * invf;
      float sn, cs;
      sincosf(ang, &sn, &cs);
      float xl = bf2f(L.u[j]), xh = bf2f(H.u[j]);
      OL.u[j] = f2bf(xl * cs - xh * sn);
      OH.u[j] = f2bf(xh * cs + xl * sn);
    }
    *reinterpret_cast<uint4*>(base) = OL.v;
    *reinterpret_cast<uint4*>(base + 64) = OH.v;
  } else {
    __shared__ ushort t[64][65];
    int local = blockIdx.x - 2560;             // 32 s-tiles x 2 d-tiles x 8 hkv
    int s0 = (local & 31) * 64;
    int d0 = ((local >> 5) & 1) * 64;
    int hkv = local >> 6;
    int tx = threadIdx.x & 63, ty = threadIdx.x >> 6;  // 64 x 4
#pragma unroll
    for (int i = 0; i < 64; i += 4)
      t[i + ty][tx] = QKV[(size_t)(s0 + i + ty) * QKV_N + HID + NKV * HD + hkv * HD + d0 + tx];
    __syncthreads();
#pragma unroll
    for (int i = 0; i < 64; i += 4)
      Vt[((size_t)hkv * HD + d0 + i + ty) * S_LEN + s0 + tx] = t[tx][i + ty];
  }
}

// ---------------- flash attention: swapped-QK^T 32x32 MFMA, in-register softmax ----------------
// 512 blocks, ONE q-panel each (vs R8's 256 blocks x 2 panels): 2 blocks/CU co-resident
// (64KB LDS x2 = 128KB <= 160KB) -> inter-block overlap hides the stage/drain (m114).
// Heavy-first: qb = 15 - (lin>>5) so panels 15..8 dispatch in the first full-chip round,
// panels 7..0 backfill. Bijective: h from lin bits 0..4, qb from bits 5..8.
// XCD-local KV preserved: hkv = lin&7 for every qb slice.
__global__ __launch_bounds__(256, 2) void attn_kernel(
    const ushort* __restrict__ QKV, const ushort* __restrict__ Vt, ushort* __restrict__ AO) {
  constexpr float SCALE = 0.08838834764831845f;  // 1/sqrt(128)
  __shared__ ushort k_lds[2][64 * 128];   // [krow][128 d], 16B chunks XOR-swizzled by (row&7)
  __shared__ ushort v_lds[2][128 * 64];   // [d][64 s], 16B chunks XOR-swizzled by (row&7)

  const int lin = blockIdx.x;
  const int h = ((lin & 7) << 2) + ((lin >> 3) & 3);
  const int qb = 15 - (lin >> 5);         // heavy panels first
  const int hkv = h >> 2;
  const int tid = threadIdx.x, wid = tid >> 6, lane = tid & 63;
  const int l32 = lane & 31;
  const int hi = lane >> 5;

  auto stageKV = [&](int buf, int kt) {
#pragma unroll
    for (int i = 0; i < 4; ++i) {
      int c = i * 256 + wid * 64 + lane;
      int row = c >> 4, ch = c & 15;
      int sch = ch ^ (row & 7);
      gload_lds16(QKV + (size_t)(kt * 64 + row) * QKV_N + HID + hkv * HD + sch * 8,
                  &k_lds[buf][c * 8]);
    }
#pragma unroll
    for (int i = 0; i < 4; ++i) {
      int c = i * 256 + wid * 64 + lane;
      int row = c >> 3, ch = c & 7;
      int sch = ch ^ (row & 7);
      gload_lds16(Vt + ((size_t)hkv * HD + row) * S_LEN + (size_t)kt * 64 + sch * 8,
                  &v_lds[buf][c * 8]);
    }
  };

  const int q0 = qb * 128;
  const int qg = q0 + wid * 32 + l32;     // this lane's q row

  bf16x8 qf[8];
  {
    const ushort* qrow = QKV + (size_t)qg * QKV_N + h * HD + hi * 8;
#pragma unroll
    for (int ds = 0; ds < 8; ++ds)
      qf[ds] = *reinterpret_cast<const bf16x8*>(qrow + ds * 16);
  }

  float m_run = -1e30f, l_run = 0.f;
  f32x16 oacc[4] = {};   // oacc[f][r] = O[q=l32][d = f*32 + crow(r,hi)]

  stageKV(0, 0);
  __syncthreads();

  const int nt = 2 * qb + 2;
  for (int kt = 0; kt < nt; ++kt) {
    const int cur = kt & 1;
    if (kt + 1 < nt) stageKV(cur ^ 1, kt + 1);

    if (kt * 64 <= q0 + wid * 32 + 31) {
      float pv[32];
      __builtin_amdgcn_s_setprio(1);
#pragma unroll
      for (int kf = 0; kf < 2; ++kf) {
        f32x16 s = {};
        int rk = kf * 32 + l32;
#pragma unroll
        for (int ds = 0; ds < 8; ++ds) {
          int c16 = (ds * 2 + hi) ^ (rk & 7);
          bf16x8 kfr = *reinterpret_cast<const bf16x8*>(&k_lds[cur][rk * 128 + c16 * 8]);
          s = __builtin_amdgcn_mfma_f32_32x32x16_bf16(kfr, qf[ds], s, 0, 0, 0);
        }
#pragma unroll
        for (int r = 0; r < 16; ++r) pv[kf * 16 + r] = s[r] * SCALE;
      }
      __builtin_amdgcn_s_setprio(0);

      if (kt * 64 + 63 > q0 + wid * 32) {  // diagonal tile: causal mask
#pragma unroll
        for (int kf = 0; kf < 2; ++kf)
#pragma unroll
          for (int r = 0; r < 16; ++r) {
            int kl = kf * 32 + (r & 3) + 8 * (r >> 2) + 4 * hi;
            if (kt * 64 + kl > qg) pv[kf * 16 + r] = -1e30f;
          }
      }

      float mt = pv[0];
#pragma unroll
      for (int i = 1; i < 32; ++i) mt = fmaxf(mt, pv[i]);
      mt = fmaxf(mt, __shfl_xor(mt, 32, 64));
      float mn = fmaxf(m_run, mt);
      float alpha = __expf(m_run - mn);
      float ls = 0.f;
#pragma unroll
      for (int i = 0; i < 32; ++i) { pv[i] = __expf(pv[i] - mn); ls += pv[i]; }
      ls += __shfl_xor(ls, 32, 64);
      l_run = l_run * alpha + ls;
      m_run = mn;
#pragma unroll
      for (int f = 0; f < 4; ++f)
#pragma unroll
        for (int r = 0; r < 16; ++r) oacc[f][r] *= alpha;

      // pack P -> PV B-operand (T12: cvt_pk + permlane32_swap)
      union PW { uint32_t w[4]; bf16x8 v; } pa[4];
#pragma unroll
      for (int ks = 0; ks < 4; ++ks) {
        uint32_t x0, x1, y0, y1;
        asm("v_cvt_pk_bf16_f32 %0, %1, %2" : "=v"(x0) : "v"(pv[8 * ks + 0]), "v"(pv[8 * ks + 1]));
        asm("v_cvt_pk_bf16_f32 %0, %1, %2" : "=v"(x1) : "v"(pv[8 * ks + 2]), "v"(pv[8 * ks + 3]));
        asm("v_cvt_pk_bf16_f32 %0, %1, %2" : "=v"(y0) : "v"(pv[8 * ks + 4]), "v"(pv[8 * ks + 5]));
        asm("v_cvt_pk_bf16_f32 %0, %1, %2" : "=v"(y1) : "v"(pv[8 * ks + 6]), "v"(pv[8 * ks + 7]));
        u32x2 r0 = __builtin_amdgcn_permlane32_swap(x0, y0, false, false);
        u32x2 r1 = __builtin_amdgcn_permlane32_swap(x1, y1, false, false);
        pa[ks].w[0] = r0.x; pa[ks].w[1] = r1.x; pa[ks].w[2] = r0.y; pa[ks].w[3] = r1.y;
      }

      __builtin_amdgcn_s_setprio(1);
#pragma unroll
      for (int ks = 0; ks < 4; ++ks) {
#pragma unroll
        for (int f = 0; f < 4; ++f) {
          int dv = f * 32 + l32;
          int c8 = (2 * ks + hi) ^ (dv & 7);
          bf16x8 vfr = *reinterpret_cast<const bf16x8*>(&v_lds[cur][dv * 64 + c8 * 8]);
          oacc[f] = __builtin_amdgcn_mfma_f32_32x32x16_bf16(vfr, pa[ks].v, oacc[f], 0, 0, 0);
        }
      }
      __builtin_amdgcn_s_setprio(0);
    }

    __syncthreads();
  }

  float inv_l = 1.0f / l_run;
  ushort* aorow = AO + (size_t)qg * HID + h * HD;
#pragma unroll
  for (int f = 0; f < 4; ++f)
#pragma unroll
    for (int g = 0; g < 4; ++g) {
      ushort4 o;
      o.x = f2bf(oacc[f][g * 4 + 0] * inv_l);
      o.y = f2bf(oacc[f][g * 4 + 1] * inv_l);
      o.z = f2bf(oacc[f][g * 4 + 2] * inv_l);
      o.w = f2bf(oacc[f][g * 4 + 3] * inv_l);
      *reinterpret_cast<ushort4*>(aorow + f * 32 + g * 8 + 4 * hi) = o;
    }
}

// ---------------- launcher ----------------
extern "C" void kernel_launch(void* const* d_in, const int* in_sizes, int n_in,
                              void* d_out, int out_size, void* d_ws, size_t ws_size,
                              hipStream_t stream) {
  (void)in_sizes; (void)n_in; (void)out_size;
  const float* hs = (const float*)d_in[0];
  const float* Wq = (const float*)d_in[1];
  const float* Wk = (const float*)d_in[2];
  const float* Wv = (const float*)d_in[3];
  const float* Wo = (const float*)d_in[4];
  float* out = (float*)d_out;

  // workspace layout (bytes)
  char* ws = (char*)d_ws;
  const size_t OFF_HSB   = 0;                         // 2048*4096 bf16 = 16 MB
  const size_t OFF_WQKVT = OFF_HSB + 16777216;        // 6144*4096 bf16 = 48 MB
  const size_t OFF_WOT   = OFF_WQKVT + 50331648;      // 4096*4096 bf16 = 32 MB
  const size_t OFF_QKV   = OFF_WOT + 33554432;        // 2048*6144 bf16 = 24 MB
  const size_t OFF_VT    = OFF_QKV + 25165824;        // 8*128*2048 bf16 = 4 MB
  const size_t OFF_AO    = OFF_VT + 4194304;          // 2048*4096 bf16 = 16 MB
  if (ws_size < OFF_AO + 16777216) return;            // ~140 MB needed

  ushort* hsb   = (ushort*)(ws + OFF_HSB);
  ushort* WqkvT = (ushort*)(ws + OFF_WQKVT);
  ushort* WoT   = (ushort*)(ws + OFF_WOT);
  ushort* QKV   = (ushort*)(ws + OFF_QKV);
  ushort* Vt    = (ushort*)(ws + OFF_VT);
  ushort* AO    = (ushort*)(ws + OFF_AO);
  // f32 partials for the K-split O-proj, overlaid on hsb+WqkvT (both dead after QKV GEMM)
  float* P0 = (float*)(ws + 0);                       // 32 MB
  float* P1 = (float*)(ws + 33554432);                // 32 MB

  prep_all<<<18432, 256, 0, stream>>>(hs, Wq, Wk, Wv, Wo, hsb, WqkvT, WoT);
  gemm_bt<true><<<dim3(QKV_N / 128, S_LEN / 128), 256, 0, stream>>>(hsb, WqkvT, QKV, S_LEN, QKV_N, HID);
  rope_and_tv<<<3072, 256, 0, stream>>>(QKV, Vt);
  attn_kernel<<<512, 256, 0, stream>>>(QKV, Vt, AO);
  gemm_o_ks<<<1024, 256, 0, stream>>>(AO, WoT, P0, P1);
  add_f32<<<8192, 256, 0, stream>>>(P0, P1, out, S_LEN * HID);
}

// Round 18
// 316.674 us; speedup vs baseline: 1.0643x; 1.0166x over previous
//
#include <hip/hip_runtime.h>
#include <cstdint>
#include <cstddef>

typedef __attribute__((ext_vector_type(4))) float f32x4;
typedef __attribute__((ext_vector_type(16))) float f32x16;
typedef __attribute__((ext_vector_type(8))) short bf16x8;
typedef __attribute__((ext_vector_type(2))) unsigned int u32x2;

#define S_LEN   2048
#define HID     4096
#define NH      32
#define NKV     8
#define HD      128
#define QKV_N   6144   /* 4096 Q + 1024 K + 1024 V */

typedef const __attribute__((address_space(1))) unsigned int* gptr_t;
typedef __attribute__((address_space(3))) unsigned int* lptr_t;

__device__ __forceinline__ void gload_lds16(const void* g, void* l) {
  __builtin_amdgcn_global_load_lds((gptr_t)g, (lptr_t)l, 16, 0, 0);
}

__device__ __forceinline__ ushort f2bf(float f) {
  union { float f; uint32_t u; } v; v.f = f;
  uint32_t r = v.u + 0x7FFFu + ((v.u >> 16) & 1u);
  return (ushort)(r >> 16);
}
__device__ __forceinline__ float bf2f(ushort u) {
  union { uint32_t u; float f; } v; v.u = ((uint32_t)u) << 16;
  return v.f;
}

// ---------------- fused prep: hs cast + all 4 weight transposes (one launch) ----------------
__global__ void prep_all(const float* __restrict__ hs,
                         const float* __restrict__ Wq, const float* __restrict__ Wk,
                         const float* __restrict__ Wv, const float* __restrict__ Wo,
                         ushort* __restrict__ hsb,
                         ushort* __restrict__ WqkvT, ushort* __restrict__ WoT) {
  int id = blockIdx.x;
  if (id < 8192) {
    int i = (id * 256 + (int)threadIdx.x) * 4;
    float4 v = *reinterpret_cast<const float4*>(hs + i);
    ushort4 o;
    o.x = f2bf(v.x); o.y = f2bf(v.y); o.z = f2bf(v.z); o.w = f2bf(v.w);
    *reinterpret_cast<ushort4*>(hsb + i) = o;
    return;
  }
  __shared__ float t[64][69];   // pad 69: read side (row=4*tx+j, col fixed) is 2-way = free
  id -= 8192;
  const float* src; ushort* dst; int C, local;
  if (id < 4096)        { src = Wq; dst = WqkvT;                      C = 4096; local = id; }
  else if (id < 5120)   { src = Wk; dst = WqkvT + (size_t)4096 * HID; C = 1024; local = id - 4096; }
  else if (id < 6144)   { src = Wv; dst = WqkvT + (size_t)5120 * HID; C = 1024; local = id - 5120; }
  else                  { src = Wo; dst = WoT;                        C = 4096; local = id - 6144; }
  const int cb = C >> 6;
  int bx = local % cb, by = local / cb;
  int tx = threadIdx.x & 15, ty = threadIdx.x >> 4;  // 16 x 16
  int r0 = by * 64, c0 = bx * 64;
#pragma unroll
  for (int i = 0; i < 4; ++i) {
    float4 v = *reinterpret_cast<const float4*>(&src[(size_t)(r0 + ty + i * 16) * C + c0 + tx * 4]);
    t[ty + i * 16][tx * 4 + 0] = v.x;
    t[ty + i * 16][tx * 4 + 1] = v.y;
    t[ty + i * 16][tx * 4 + 2] = v.z;
    t[ty + i * 16][tx * 4 + 3] = v.w;
  }
  __syncthreads();
#pragma unroll
  for (int i = 0; i < 4; ++i) {
    int cc = ty + i * 16;
    ushort4 o;
    o.x = f2bf(t[tx * 4 + 0][cc]);
    o.y = f2bf(t[tx * 4 + 1][cc]);
    o.z = f2bf(t[tx * 4 + 2][cc]);
    o.w = f2bf(t[tx * 4 + 3][cc]);
    *reinterpret_cast<ushort4*>(&dst[(size_t)(c0 + cc) * 4096 + r0 + tx * 4]) = o;
  }
}

// ---------------- GEMM: C[M][N] = A[M][K] * B^T  (B stored [N][K]), bf16 in, fp32 acc ----------------
// m97 structure, BK=64 (R14/R17-measured: ~103us / MfmaUtil 44%). No XCD swizzle
// (R15: -12us in this L3-fit regime).
template <bool BF16_OUT>
__global__ __launch_bounds__(256, 4) void gemm_bt(
    const ushort* __restrict__ A, const ushort* __restrict__ B,
    void* __restrict__ Cp, int M, int N, int K) {
  __shared__ ushort a_lds[128 * 64];
  __shared__ ushort b_lds[128 * 64];
  const int tid = threadIdx.x;
  const int wid = tid >> 6, lane = tid & 63;
  const int l16 = lane & 15, lk = lane >> 4;
  const int wr = wid >> 1, wc = wid & 1;
  const size_t a_row0 = (size_t)blockIdx.y * 128;
  const size_t b_row0 = (size_t)blockIdx.x * 128;

  f32x4 acc[4][4] = {};

  for (int kt = 0; kt < K; kt += 64) {
    __syncthreads();  // prior-iteration LDS reads complete before overwrite
#pragma unroll
    for (int i = 0; i < 4; ++i) {
      int c = i * 256 + tid;               // 1024 16B-chunks per tile (8 per 128B row)
      int row = c >> 3, pos = c & 7;
      int src = pos ^ (row & 7);           // involution: pre-swizzled source
      gload_lds16(A + (a_row0 + row) * K + kt + src * 8, &a_lds[c * 8]);
      gload_lds16(B + (b_row0 + row) * K + kt + src * 8, &b_lds[c * 8]);
    }
    __syncthreads();  // drains vmcnt: LDS tiles ready

#pragma unroll
    for (int kk = 0; kk < 2; ++kk) {
      bf16x8 af[4], bf[4];
#pragma unroll
      for (int m = 0; m < 4; ++m) {
        int row = wr * 64 + m * 16 + l16;
        int ch = (kk * 4 + lk) ^ (row & 7);
        af[m] = *reinterpret_cast<const bf16x8*>(&a_lds[row * 64 + ch * 8]);
      }
#pragma unroll
      for (int n = 0; n < 4; ++n) {
        int row = wc * 64 + n * 16 + l16;
        int ch = (kk * 4 + lk) ^ (row & 7);
        bf[n] = *reinterpret_cast<const bf16x8*>(&b_lds[row * 64 + ch * 8]);
      }
#pragma unroll
      for (int m = 0; m < 4; ++m)
#pragma unroll
        for (int n = 0; n < 4; ++n)
          acc[m][n] = __builtin_amdgcn_mfma_f32_16x16x32_bf16(af[m], bf[n], acc[m][n], 0, 0, 0);
    }
  }

#pragma unroll
  for (int m = 0; m < 4; ++m) {
    int row_b = wr * 64 + m * 16 + lk * 4;
#pragma unroll
    for (int n = 0; n < 4; ++n) {
      int col = (int)b_row0 + wc * 64 + n * 16 + l16;
#pragma unroll
      for (int r = 0; r < 4; ++r) {
        size_t row = a_row0 + row_b + r;
        if constexpr (BF16_OUT)
          ((ushort*)Cp)[row * N + col] = f2bf(acc[m][n][r]);
        else
          ((float*)Cp)[row * N + col] = acc[m][n][r];
      }
    }
  }
}

// ---------------- O-proj GEMM, K-split x2 (4 blocks/CU), BK=64, bf16 partials ----------------
// f32-accumulated, rounded ONCE to bf16 per partial (P0/P1 16MB each) -> halves the
// K-split reduction traffic (R17: 128MB overhead -> 64MB). Precision: adds <=0.01 absmax
// (margin 0.03 vs 0.152 threshold).
__global__ __launch_bounds__(256, 4) void gemm_o_ks(
    const ushort* __restrict__ A, const ushort* __restrict__ B,
    ushort* __restrict__ P0, ushort* __restrict__ P1) {
  __shared__ ushort a_lds[128 * 64];
  __shared__ ushort b_lds[128 * 64];
  const int bid = blockIdx.x;
  const int kh = bid >> 9;
  const int rem = bid & 511;
  const size_t b_row0 = (size_t)(rem & 31) * 128;   // N/128 = 32
  const size_t a_row0 = (size_t)(rem >> 5) * 128;   // M/128 = 16
  const int k0 = kh * 2048, k1 = k0 + 2048;
  ushort* __restrict__ P = kh ? P1 : P0;
  const int tid = threadIdx.x;
  const int wid = tid >> 6, lane = tid & 63;
  const int l16 = lane & 15, lk = lane >> 4;
  const int wr = wid >> 1, wc = wid & 1;

  f32x4 acc[4][4] = {};

  for (int kt = k0; kt < k1; kt += 64) {
    __syncthreads();
#pragma unroll
    for (int i = 0; i < 4; ++i) {
      int c = i * 256 + tid;
      int row = c >> 3, pos = c & 7;
      int src = pos ^ (row & 7);
      gload_lds16(A + (a_row0 + row) * HID + kt + src * 8, &a_lds[c * 8]);
      gload_lds16(B + (b_row0 + row) * HID + kt + src * 8, &b_lds[c * 8]);
    }
    __syncthreads();

#pragma unroll
    for (int kk = 0; kk < 2; ++kk) {
      bf16x8 af[4], bf[4];
#pragma unroll
      for (int m = 0; m < 4; ++m) {
        int row = wr * 64 + m * 16 + l16;
        int ch = (kk * 4 + lk) ^ (row & 7);
        af[m] = *reinterpret_cast<const bf16x8*>(&a_lds[row * 64 + ch * 8]);
      }
#pragma unroll
      for (int n = 0; n < 4; ++n) {
        int row = wc * 64 + n * 16 + l16;
        int ch = (kk * 4 + lk) ^ (row & 7);
        bf[n] = *reinterpret_cast<const bf16x8*>(&b_lds[row * 64 + ch * 8]);
      }
#pragma unroll
      for (int m = 0; m < 4; ++m)
#pragma unroll
        for (int n = 0; n < 4; ++n)
          acc[m][n] = __builtin_amdgcn_mfma_f32_16x16x32_bf16(af[m], bf[n], acc[m][n], 0, 0, 0);
    }
  }

#pragma unroll
  for (int m = 0; m < 4; ++m) {
    int row_b = wr * 64 + m * 16 + lk * 4;
#pragma unroll
    for (int n = 0; n < 4; ++n) {
      int col = (int)b_row0 + wc * 64 + n * 16 + l16;
#pragma unroll
      for (int r = 0; r < 4; ++r)
        P[(a_row0 + row_b + r) * HID + col] = f2bf(acc[m][n][r]);
    }
  }
}

// sum two bf16 partials -> f32 out (vectorized: 8 elems/thread)
__global__ void add_bf16_f32(const ushort* __restrict__ a, const ushort* __restrict__ b,
                             float* __restrict__ o, int n) {
  int i = (blockIdx.x * 256 + threadIdx.x) * 8;
  if (i >= n) return;
  ushort4 xa0 = *reinterpret_cast<const ushort4*>(a + i);
  ushort4 xa1 = *reinterpret_cast<const ushort4*>(a + i + 4);
  ushort4 xb0 = *reinterpret_cast<const ushort4*>(b + i);
  ushort4 xb1 = *reinterpret_cast<const ushort4*>(b + i + 4);
  float4 o0, o1;
  o0.x = bf2f(xa0.x) + bf2f(xb0.x); o0.y = bf2f(xa0.y) + bf2f(xb0.y);
  o0.z = bf2f(xa0.z) + bf2f(xb0.z); o0.w = bf2f(xa0.w) + bf2f(xb0.w);
  o1.x = bf2f(xa1.x) + bf2f(xb1.x); o1.y = bf2f(xa1.y) + bf2f(xb1.y);
  o1.z = bf2f(xa1.z) + bf2f(xb1.z); o1.w = bf2f(xa1.w) + bf2f(xb1.w);
  *reinterpret_cast<float4*>(o + i) = o0;
  *reinterpret_cast<float4*>(o + i + 4) = o1;
}

// ---------------- fused RoPE (Q/K cols) + V transpose — independent QKV regions ----------------
__global__ void rope_and_tv(ushort* __restrict__ QKV, ushort* __restrict__ Vt) {
  if (blockIdx.x < 2560) {
    int idx = blockIdx.x * 256 + threadIdx.x;  // 2048 * 40 * 8 threads
    int dg = idx & 7;
    int t = idx >> 3;
    int s = t / 40;
    int hh = t - s * 40;
    if (s >= S_LEN) return;
    int col = (hh < NH) ? hh * HD : HID + (hh - NH) * HD;
    ushort* base = QKV + (size_t)s * QKV_N + col + dg * 8;

    union U { uint4 v; ushort u[8]; };
    U L, H, OL, OH;
    L.v = *reinterpret_cast<const uint4*>(base);
    H.v = *reinterpret_cast<const uint4*>(base + 64);
    const float C0 = 13.287712379549449f / 64.0f;  // log2(10000)/64
#pragma unroll
    for (int j = 0; j < 8; ++j) {
      int d = dg * 8 + j;
      float invf = exp2f(-(float)d * C0);
      float ang = (float)s * invf;
      float sn, cs;
      sincosf(ang, &sn, &cs);
      float xl = bf2f(L.u[j]), xh = bf2f(H.u[j]);
      OL.u[j] = f2bf(xl * cs - xh * sn);
      OH.u[j] = f2bf(xh * cs + xl * sn);
    }
    *reinterpret_cast<uint4*>(base) = OL.v;
    *reinterpret_cast<uint4*>(base + 64) = OH.v;
  } else {
    __shared__ ushort t[64][65];
    int local = blockIdx.x - 2560;             // 32 s-tiles x 2 d-tiles x 8 hkv
    int s0 = (local & 31) * 64;
    int d0 = ((local >> 5) & 1) * 64;
    int hkv = local >> 6;
    int tx = threadIdx.x & 63, ty = threadIdx.x >> 6;  // 64 x 4
#pragma unroll
    for (int i = 0; i < 64; i += 4)
      t[i + ty][tx] = QKV[(size_t)(s0 + i + ty) * QKV_N + HID + NKV * HD + hkv * HD + d0 + tx];
    __syncthreads();
#pragma unroll
    for (int i = 0; i < 64; i += 4)
      Vt[((size_t)hkv * HD + d0 + i + ty) * S_LEN + s0 + tx] = t[tx][i + ty];
  }
}

// ---------------- flash attention: swapped-QK^T 32x32 MFMA, in-register softmax ----------------
// R17-proven: 512 blocks, one q-panel each, 2 blocks/CU co-resident, heavy-first,
// XCD-local KV (hkv = lin&7 -> 1MB per XCD L2).
__global__ __launch_bounds__(256, 2) void attn_kernel(
    const ushort* __restrict__ QKV, const ushort* __restrict__ Vt, ushort* __restrict__ AO) {
  constexpr float SCALE = 0.08838834764831845f;  // 1/sqrt(128)
  __shared__ ushort k_lds[2][64 * 128];   // [krow][128 d], 16B chunks XOR-swizzled by (row&7)
  __shared__ ushort v_lds[2][128 * 64];   // [d][64 s], 16B chunks XOR-swizzled by (row&7)

  const int lin = blockIdx.x;
  const int h = ((lin & 7) << 2) + ((lin >> 3) & 3);
  const int qb = 15 - (lin >> 5);         // heavy panels first
  const int hkv = h >> 2;
  const int tid = threadIdx.x, wid = tid >> 6, lane = tid & 63;
  const int l32 = lane & 31;
  const int hi = lane >> 5;

  auto stageKV = [&](int buf, int kt) {
#pragma unroll
    for (int i = 0; i < 4; ++i) {
      int c = i * 256 + wid * 64 + lane;
      int row = c >> 4, ch = c & 15;
      int sch = ch ^ (row & 7);
      gload_lds16(QKV + (size_t)(kt * 64 + row) * QKV_N + HID + hkv * HD + sch * 8,
                  &k_lds[buf][c * 8]);
    }
#pragma unroll
    for (int i = 0; i < 4; ++i) {
      int c = i * 256 + wid * 64 + lane;
      int row = c >> 3, ch = c & 7;
      int sch = ch ^ (row & 7);
      gload_lds16(Vt + ((size_t)hkv * HD + row) * S_LEN + (size_t)kt * 64 + sch * 8,
                  &v_lds[buf][c * 8]);
    }
  };

  const int q0 = qb * 128;
  const int qg = q0 + wid * 32 + l32;     // this lane's q row

  bf16x8 qf[8];
  {
    const ushort* qrow = QKV + (size_t)qg * QKV_N + h * HD + hi * 8;
#pragma unroll
    for (int ds = 0; ds < 8; ++ds)
      qf[ds] = *reinterpret_cast<const bf16x8*>(qrow + ds * 16);
  }

  float m_run = -1e30f, l_run = 0.f;
  f32x16 oacc[4] = {};   // oacc[f][r] = O[q=l32][d = f*32 + crow(r,hi)]

  stageKV(0, 0);
  __syncthreads();

  const int nt = 2 * qb + 2;
  for (int kt = 0; kt < nt; ++kt) {
    const int cur = kt & 1;
    if (kt + 1 < nt) stageKV(cur ^ 1, kt + 1);

    if (kt * 64 <= q0 + wid * 32 + 31) {
      float pv[32];
      __builtin_amdgcn_s_setprio(1);
#pragma unroll
      for (int kf = 0; kf < 2; ++kf) {
        f32x16 s = {};
        int rk = kf * 32 + l32;
#pragma unroll
        for (int ds = 0; ds < 8; ++ds) {
          int c16 = (ds * 2 + hi) ^ (rk & 7);
          bf16x8 kfr = *reinterpret_cast<const bf16x8*>(&k_lds[cur][rk * 128 + c16 * 8]);
          s = __builtin_amdgcn_mfma_f32_32x32x16_bf16(kfr, qf[ds], s, 0, 0, 0);
        }
#pragma unroll
        for (int r = 0; r < 16; ++r) pv[kf * 16 + r] = s[r] * SCALE;
      }
      __builtin_amdgcn_s_setprio(0);

      if (kt * 64 + 63 > q0 + wid * 32) {  // diagonal tile: causal mask
#pragma unroll
        for (int kf = 0; kf < 2; ++kf)
#pragma unroll
          for (int r = 0; r < 16; ++r) {
            int kl = kf * 32 + (r & 3) + 8 * (r >> 2) + 4 * hi;
            if (kt * 64 + kl > qg) pv[kf * 16 + r] = -1e30f;
          }
      }

      float mt = pv[0];
#pragma unroll
      for (int i = 1; i < 32; ++i) mt = fmaxf(mt, pv[i]);
      mt = fmaxf(mt, __shfl_xor(mt, 32, 64));
      float mn = fmaxf(m_run, mt);
      float alpha = __expf(m_run - mn);
      float ls = 0.f;
#pragma unroll
      for (int i = 0; i < 32; ++i) { pv[i] = __expf(pv[i] - mn); ls += pv[i]; }
      ls += __shfl_xor(ls, 32, 64);
      l_run = l_run * alpha + ls;
      m_run = mn;
#pragma unroll
      for (int f = 0; f < 4; ++f)
#pragma unroll
        for (int r = 0; r < 16; ++r) oacc[f][r] *= alpha;

      // pack P -> PV B-operand (T12: cvt_pk + permlane32_swap)
      union PW { uint32_t w[4]; bf16x8 v; } pa[4];
#pragma unroll
      for (int ks = 0; ks < 4; ++ks) {
        uint32_t x0, x1, y0, y1;
        asm("v_cvt_pk_bf16_f32 %0, %1, %2" : "=v"(x0) : "v"(pv[8 * ks + 0]), "v"(pv[8 * ks + 1]));
        asm("v_cvt_pk_bf16_f32 %0, %1, %2" : "=v"(x1) : "v"(pv[8 * ks + 2]), "v"(pv[8 * ks + 3]));
        asm("v_cvt_pk_bf16_f32 %0, %1, %2" : "=v"(y0) : "v"(pv[8 * ks + 4]), "v"(pv[8 * ks + 5]));
        asm("v_cvt_pk_bf16_f32 %0, %1, %2" : "=v"(y1) : "v"(pv[8 * ks + 6]), "v"(pv[8 * ks + 7]));
        u32x2 r0 = __builtin_amdgcn_permlane32_swap(x0, y0, false, false);
        u32x2 r1 = __builtin_amdgcn_permlane32_swap(x1, y1, false, false);
        pa[ks].w[0] = r0.x; pa[ks].w[1] = r1.x; pa[ks].w[2] = r0.y; pa[ks].w[3] = r1.y;
      }

      __builtin_amdgcn_s_setprio(1);
#pragma unroll
      for (int ks = 0; ks < 4; ++ks) {
#pragma unroll
        for (int f = 0; f < 4; ++f) {
          int dv = f * 32 + l32;
          int c8 = (2 * ks + hi) ^ (dv & 7);
          bf16x8 vfr = *reinterpret_cast<const bf16x8*>(&v_lds[cur][dv * 64 + c8 * 8]);
          oacc[f] = __builtin_amdgcn_mfma_f32_32x32x16_bf16(vfr, pa[ks].v, oacc[f], 0, 0, 0);
        }
      }
      __builtin_amdgcn_s_setprio(0);
    }

    __syncthreads();
  }

  float inv_l = 1.0f / l_run;
  ushort* aorow = AO + (size_t)qg * HID + h * HD;
#pragma unroll
  for (int f = 0; f < 4; ++f)
#pragma unroll
    for (int g = 0; g < 4; ++g) {
      ushort4 o;
      o.x = f2bf(oacc[f][g * 4 + 0] * inv_l);
      o.y = f2bf(oacc[f][g * 4 + 1] * inv_l);
      o.z = f2bf(oacc[f][g * 4 + 2] * inv_l);
      o.w = f2bf(oacc[f][g * 4 + 3] * inv_l);
      *reinterpret_cast<ushort4*>(aorow + f * 32 + g * 8 + 4 * hi) = o;
    }
}

// ---------------- launcher ----------------
extern "C" void kernel_launch(void* const* d_in, const int* in_sizes, int n_in,
                              void* d_out, int out_size, void* d_ws, size_t ws_size,
                              hipStream_t stream) {
  (void)in_sizes; (void)n_in; (void)out_size;
  const float* hs = (const float*)d_in[0];
  const float* Wq = (const float*)d_in[1];
  const float* Wk = (const float*)d_in[2];
  const float* Wv = (const float*)d_in[3];
  const float* Wo = (const float*)d_in[4];
  float* out = (float*)d_out;

  // workspace layout (bytes)
  char* ws = (char*)d_ws;
  const size_t OFF_HSB   = 0;                         // 2048*4096 bf16 = 16 MB
  const size_t OFF_WQKVT = OFF_HSB + 16777216;        // 6144*4096 bf16 = 48 MB
  const size_t OFF_WOT   = OFF_WQKVT + 50331648;      // 4096*4096 bf16 = 32 MB
  const size_t OFF_QKV   = OFF_WOT + 33554432;        // 2048*6144 bf16 = 24 MB
  const size_t OFF_VT    = OFF_QKV + 25165824;        // 8*128*2048 bf16 = 4 MB
  const size_t OFF_AO    = OFF_VT + 4194304;          // 2048*4096 bf16 = 16 MB
  if (ws_size < OFF_AO + 16777216) return;            // ~140 MB needed

  ushort* hsb   = (ushort*)(ws + OFF_HSB);
  ushort* WqkvT = (ushort*)(ws + OFF_WQKVT);
  ushort* WoT   = (ushort*)(ws + OFF_WOT);
  ushort* QKV   = (ushort*)(ws + OFF_QKV);
  ushort* Vt    = (ushort*)(ws + OFF_VT);
  ushort* AO    = (ushort*)(ws + OFF_AO);
  // bf16 partials for the K-split O-proj, overlaid on hsb (dead after QKV GEMM): 2x16MB
  ushort* P0 = (ushort*)(ws + 0);
  ushort* P1 = (ushort*)(ws + 16777216);

  prep_all<<<18432, 256, 0, stream>>>(hs, Wq, Wk, Wv, Wo, hsb, WqkvT, WoT);
  gemm_bt<true><<<dim3(QKV_N / 128, S_LEN / 128), 256, 0, stream>>>(hsb, WqkvT, QKV, S_LEN, QKV_N, HID);
  rope_and_tv<<<3072, 256, 0, stream>>>(QKV, Vt);
  attn_kernel<<<512, 256, 0, stream>>>(QKV, Vt, AO);
  gemm_o_ks<<<1024, 256, 0, stream>>>(AO, WoT, P0, P1);
  add_bf16_f32<<<4096, 256, 0, stream>>>(P0, P1, out, S_LEN * HID);
}